// Round 1
// 1122.088 us; speedup vs baseline: 1.1439x; 1.1439x over previous
//
#include <hip/hip_runtime.h>
#include <math.h>

#define BATCH 16
#define SRCLEN 128
#define DIM 512
#define VOCABSZ 32000
#define BEAM 4
#define MAXLEN 16
#define NROWS (BATCH*BEAM)   // 64
#define BOS_TOK 1
#define EOS_TOK 2
#define NEGINF 1e9f
#define CHUNKS 8
#define CHUNK 4000           // VOCABSZ / CHUNKS
#define PCH 8                // pool s-chunks
#define PCL (SRCLEN/PCH)     // 16 s per chunk

// ---------------- key pack/unpack: (ordered float << 32) | (0xFFFFFFFF - id) ----------------
__device__ inline unsigned long long packkey(float v, int idx) {
    unsigned int fb = __float_as_uint(v);
    fb = fb ^ ((fb >> 31) ? 0xFFFFFFFFu : 0x80000000u);
    return ((unsigned long long)fb << 32) | (unsigned long long)(0xFFFFFFFFu - (unsigned int)idx);
}
__device__ inline float unpack_val(unsigned long long k) {
    unsigned int fb = (unsigned int)(k >> 32);
    fb = fb ^ ((fb >> 31) ? 0x80000000u : 0xFFFFFFFFu);
    return __uint_as_float(fb);
}
__device__ inline int unpack_id(unsigned long long k) {
    return (int)(0xFFFFFFFFu - (unsigned int)(k & 0xFFFFFFFFu));
}
__device__ inline unsigned long long shflxor64(unsigned long long x, int mask) {
    unsigned int lo = (unsigned int)x, hi = (unsigned int)(x >> 32);
    lo = (unsigned int)__shfl_xor((int)lo, mask, 64);
    hi = (unsigned int)__shfl_xor((int)hi, mask, 64);
    return ((unsigned long long)hi << 32) | (unsigned long long)lo;
}
__device__ inline unsigned long long wavemax64(unsigned long long k) {
#pragma unroll
    for (int off = 1; off < 64; off <<= 1) {
        unsigned long long o = shflxor64(k, off);
        k = (o > k) ? o : k;
    }
    return k;
}

// ---------------- encoder pool, phase 1: per-(b, s-chunk) partial sum + count ----------------
__global__ __launch_bounds__(512) void k_pool2(const int* __restrict__ src,
                                               const float* __restrict__ Esrc,
                                               float* __restrict__ pp, float* __restrict__ pcnt) {
    int b = blockIdx.x, c = blockIdx.y;
    int d = threadIdx.x;
    float acc = 0.f, cnt = 0.f;
#pragma unroll
    for (int s = 0; s < PCL; ++s) {
        int tok = src[b * SRCLEN + c * PCL + s];
        if (tok != 0) { acc += Esrc[(size_t)tok * DIM + d]; cnt += 1.f; }
    }
    pp[(b * PCH + c) * DIM + d] = acc;
    if (d == 0) pcnt[b * PCH + c] = cnt;
}

// ---------------- encoder pool, phase 2: reduce chunks (ascending, deterministic) ----------------
__global__ __launch_bounds__(512) void k_poolred(const float* __restrict__ pp,
                                                 const float* __restrict__ pcnt,
                                                 float* __restrict__ pooled) {
    int b = blockIdx.x;
    int d = threadIdx.x;
    float acc = 0.f, cnt = 0.f;
#pragma unroll
    for (int c = 0; c < PCH; ++c) { acc += pp[(b * PCH + c) * DIM + d]; cnt += pcnt[b * PCH + c]; }
    pooled[b * DIM + d] = acc / fmaxf(cnt, 1.f);
}

// ---------------- state init ----------------
__global__ __launch_bounds__(1024) void k_init(int* __restrict__ alive_seq, float* __restrict__ alive_lp,
                                               int* __restrict__ fin_seq, float* __restrict__ fin_scores,
                                               int* __restrict__ fin_flags, int* __restrict__ batch_fin) {
    int tid = threadIdx.x;  // 1024 = NROWS*MAXLEN
    alive_seq[tid] = (tid % MAXLEN == 0) ? BOS_TOK : 0;
    fin_seq[tid] = 0;
    if (tid < NROWS) {
        alive_lp[tid] = (tid % BEAM == 0) ? 0.f : -INFINITY;
        fin_scores[tid] = -NEGINF;
        fin_flags[tid] = 0;
    }
    if (tid < BATCH) batch_fin[tid] = 0;
}

// ---------------- decoder input, transposed: xT[d][i] = E_tgt[last_i][d] + pooled[i/4][d] ----------------
__global__ __launch_bounds__(512) void k_x(const float* __restrict__ Etgt,
                                           const float* __restrict__ pooled,
                                           const int* __restrict__ alive_seq, int t,
                                           float* __restrict__ xT) {
    int i = blockIdx.x;   // row 0..63
    int d = threadIdx.x;  // 0..511
    int last = alive_seq[i * MAXLEN + t];
    float v = Etgt[(size_t)last * DIM + d] + pooled[(i >> 2) * DIM + d];
    xT[d * NROWS + i] = v;
}

// ---------------- logits GEMM, split-K, 16-row threads ----------------
// R7: thread = 1v x 16 rows (acc[16], ~40 VGPR -> no spill, 8 waves/SIMD OK);
// block = 64v x 4 row-quarters; grid 500 x 4 = 2000 blocks -> ~31 waves/CU.
// d-order per slab unchanged -> partials bit-identical.
template<int DLEN>
__global__ __launch_bounds__(256) void k_gemm4(const float* __restrict__ xT,
                                               const float* __restrict__ W,
                                               float* __restrict__ partial) {
    int v  = blockIdx.x * 64 + (threadIdx.x & 63);
    int rq = __builtin_amdgcn_readfirstlane(threadIdx.x >> 6);  // wave-uniform row quarter
    int r0 = rq * 16;
    int z  = blockIdx.z;
    int d0 = z * DLEN;
    float acc[16];
#pragma unroll
    for (int i = 0; i < 16; ++i) acc[i] = 0.f;
    const float* wp = W + (size_t)d0 * VOCABSZ + v;
    const float* xp = xT + (size_t)d0 * NROWS + r0;
    for (int dd = 0; dd < DLEN; dd += 4) {
        float w0 = wp[0];
        float w1 = wp[(size_t)VOCABSZ];
        float w2 = wp[(size_t)2 * VOCABSZ];
        float w3 = wp[(size_t)3 * VOCABSZ];
        wp += (size_t)4 * VOCABSZ;
        const float* x0 = xp;
        const float* x1 = xp + NROWS;
        const float* x2 = xp + 2 * NROWS;
        const float* x3 = xp + 3 * NROWS;
        xp += 4 * NROWS;
#pragma unroll
        for (int i = 0; i < 16; ++i) acc[i] = fmaf(x0[i], w0, acc[i]);
#pragma unroll
        for (int i = 0; i < 16; ++i) acc[i] = fmaf(x1[i], w1, acc[i]);
#pragma unroll
        for (int i = 0; i < 16; ++i) acc[i] = fmaf(x2[i], w2, acc[i]);
#pragma unroll
        for (int i = 0; i < 16; ++i) acc[i] = fmaf(x3[i], w3, acc[i]);
    }
    float* op = partial + (size_t)z * NROWS * VOCABSZ + (size_t)r0 * VOCABSZ + v;
#pragma unroll
    for (int i = 0; i < 16; ++i) op[(size_t)i * VOCABSZ] = acc[i];
}

// ---------------- per-(row,chunk): partial max, sumexp, top-8 ----------------
// R8: old k_part was grid-limited (512 blocks x 256 thr = 8 waves/CU = 22% occ)
// and barrier-bound (8-round smem-tree merge = ~80 __syncthreads/block) ->
// 76us at 224 GB/s (2.8% HBM). Now 1024 threads (32 waves/CU), 1 float4/slab
// per thread (all loads independent/in-flight), and a 4-barrier merge:
// sort-4 network -> per-wave top-8 via shfl wave-max rounds (k_mergesel's
// proven pattern) -> 128 keys in LDS -> wave0 extracts block top-8.
// Output layout (pm/ps/ptopv/ptopi, 8-chunk granularity) unchanged -> mergesel untouched.
// sumexp reassociated (butterfly vs tree): same ~1e-6 class as prior accepted chunking.
template<int NZ>
__global__ __launch_bounds__(1024) void k_part(const float* __restrict__ partial,
                                               const float* __restrict__ bias,
                                               float* __restrict__ pm, float* __restrict__ ps,
                                               float* __restrict__ ptopv, int* __restrict__ ptopi) {
    int row = blockIdx.x, ch = blockIdx.y;
    int tid = threadIdx.x;
    int lane = tid & 63;
    int wv = tid >> 6;                    // 0..15
    const size_t slab = (size_t)NROWS * VOCABSZ;
    const bool valid = tid < (CHUNK / 4); // 1000 float4 positions

    float vals[4] = {-INFINITY, -INFINITY, -INFINITY, -INFINITY};
    if (valid) {
        const float4* l0 = (const float4*)(partial + (size_t)row * VOCABSZ + ch * CHUNK);
        float4 q = l0[tid];
#pragma unroll
        for (int zz = 1; zz < NZ; ++zz) {
            const float4* lz = (const float4*)(partial + slab * zz + (size_t)row * VOCABSZ + ch * CHUNK);
            float4 q2 = lz[tid];
            q.x += q2.x; q.y += q2.y; q.z += q2.z; q.w += q2.w;
        }
        float4 bb = ((const float4*)(bias + ch * CHUNK))[tid];
        vals[0] = q.x + bb.x; vals[1] = q.y + bb.y; vals[2] = q.z + bb.z; vals[3] = q.w + bb.w;
    }

    // ---- block max: wave butterfly + 16-entry LDS combine ----
    float m_t = fmaxf(fmaxf(vals[0], vals[1]), fmaxf(vals[2], vals[3]));
#pragma unroll
    for (int off = 1; off < 64; off <<= 1) m_t = fmaxf(m_t, __shfl_xor(m_t, off, 64));
    __shared__ float swred[16];
    if (lane == 0) swred[wv] = m_t;
    __syncthreads();
    float m = swred[0];
#pragma unroll
    for (int w = 1; w < 16; ++w) m = fmaxf(m, swred[w]);
    __syncthreads();   // swred reused for sums below

    // ---- block sumexp ----
    float se = 0.f;
    if (valid) {
#pragma unroll
        for (int c = 0; c < 4; ++c) se += expf(vals[c] - m);
    }
#pragma unroll
    for (int off = 1; off < 64; off <<= 1) se += __shfl_xor(se, off, 64);
    if (lane == 0) swred[wv] = se;
    __syncthreads();
    if (tid == 0) {
        float s = 0.f;
#pragma unroll
        for (int w = 0; w < 16; ++w) s += swred[w];
        pm[row * CHUNKS + ch] = m;
        ps[row * CHUNKS + ch] = s;
    }

    // ---- top-8: per-lane sort-4 -> per-wave 8 rounds wave-max -> 128-key final ----
    int gi = ch * CHUNK + tid * 4;
    unsigned long long k0 = 0ULL, k1 = 0ULL, k2 = 0ULL, k3 = 0ULL;
    if (valid) {   // keys never 0 for real values (idx < 2^31) -> 0 is a safe sentinel
        k0 = packkey(vals[0], gi);
        k1 = packkey(vals[1], gi + 1);
        k2 = packkey(vals[2], gi + 2);
        k3 = packkey(vals[3], gi + 3);
    }
    {
        unsigned long long tswp;
#define CSW(a,b) if (b > a) { tswp = a; a = b; b = tswp; }
        CSW(k0,k1) CSW(k2,k3) CSW(k0,k2) CSW(k1,k3) CSW(k1,k2)
#undef CSW
    }
    __shared__ unsigned long long skey[128];
    {
        int pos = 0;
        unsigned long long wtop[8];
#pragma unroll
        for (int r = 0; r < 8; ++r) {
            unsigned long long head = (pos == 0) ? k0 : (pos == 1) ? k1 :
                                      (pos == 2) ? k2 : (pos == 3) ? k3 : 0ULL;
            unsigned long long mx = wavemax64(head);
            if (head == mx && head != 0ULL) pos++;   // unique keys -> exactly one winner
            wtop[r] = mx;
        }
        if (lane == 0) {
#pragma unroll
            for (int r = 0; r < 8; ++r) skey[wv * 8 + r] = wtop[r];
        }
    }
    __syncthreads();
    if (tid < 64) {   // wave 0 exactly; no barriers below
        unsigned long long a = skey[tid];
        unsigned long long b2 = skey[64 + tid];
        unsigned long long hi = (a > b2) ? a : b2;
        unsigned long long lo = (a > b2) ? b2 : a;
        float* otv = ptopv + ((size_t)row * CHUNKS + ch) * 8;
        int*   oti = ptopi + ((size_t)row * CHUNKS + ch) * 8;
        int pos = 0;
#pragma unroll
        for (int r = 0; r < 8; ++r) {
            unsigned long long head = (pos == 0) ? hi : (pos == 1) ? lo : 0ULL;
            unsigned long long mx = wavemax64(head);
            if (head == mx && head != 0ULL) pos++;
            if (tid == 0) { otv[r] = unpack_val(mx); oti[r] = unpack_id(mx); }
        }
    }
}

// ---------------- merge + beam bookkeeping, one block (one wave) per batch ----------------
__global__ __launch_bounds__(64) void k_mergesel(const float* __restrict__ pm, const float* __restrict__ ps,
                                                 const float* __restrict__ ptopv, const int* __restrict__ ptopi,
                                                 int* __restrict__ alive_seq, float* __restrict__ alive_lp,
                                                 int* __restrict__ fin_seq, float* __restrict__ fin_scores,
                                                 int* __restrict__ fin_flags, int* __restrict__ batch_fin, int t) {
    int b = blockIdx.x;
    int tid = threadIdx.x;
    __shared__ int aseq_old[BEAM][MAXLEN]; __shared__ int fseq_old[BEAM][MAXLEN];
    __shared__ float s_tlp[8]; __shared__ int s_ttok[8], s_tbeam[8];
    __shared__ int s_aidx[4], s_fidx[4];
    __shared__ float s_nfsc[4]; __shared__ int s_nffl[4];
    float lpen = (float)(t + 1);

    { int k = tid >> 4, p = tid & 15;
      aseq_old[k][p] = alive_seq[(b * BEAM + k) * MAXLEN + p];
      fseq_old[k][p] = fin_seq[(b * BEAM + k) * MAXLEN + p]; }

    float rv[4]; int ri[4];
#pragma unroll
    for (int k = 0; k < 4; ++k) {
        rv[k] = ptopv[(size_t)(b * BEAM + k) * 64 + tid];
        ri[k] = ptopi[(size_t)(b * BEAM + k) * 64 + tid];
    }

    float alp[4], fsc[4]; int ffl[4];
#pragma unroll
    for (int k = 0; k < 4; ++k) {
        alp[k] = alive_lp[b * BEAM + k];
        fsc[k] = fin_scores[b * BEAM + k];
        ffl[k] = fin_flags[b * BEAM + k];
    }
    int bf_old = batch_fin[b];

    float srm[4], srl[4];
#pragma unroll
    for (int k = 0; k < 4; ++k) {
        float m = -INFINITY;
#pragma unroll
        for (int c = 0; c < CHUNKS; ++c) m = fmaxf(m, pm[(b * BEAM + k) * CHUNKS + c]);
        float s = 0.f;
#pragma unroll
        for (int c = 0; c < CHUNKS; ++c) s += ps[(b * BEAM + k) * CHUNKS + c] * expf(pm[(b * BEAM + k) * CHUNKS + c] - m);
        srm[k] = m; srl[k] = logf(s);
    }

    unsigned long long key[4];
#pragma unroll
    for (int k = 0; k < 4; ++k) {
        float sh = rv[k] - srm[k];
        float lp = sh - srl[k];
        float full = alp[k] + lp;
        float cv = full / lpen;
        key[k] = packkey(cv, k * VOCABSZ + ri[k]);
    }
    {
        unsigned long long tmp;
#define CSW(a,b) if (key[b] > key[a]) { tmp = key[a]; key[a] = key[b]; key[b] = tmp; }
        CSW(0,1) CSW(2,3) CSW(0,2) CSW(1,3) CSW(1,2)
#undef CSW
    }

    float tscore[8], tlp[8]; int ttok[8], tbeam[8], tfin[8];
    int pos = 0;
#pragma unroll
    for (int r = 0; r < 8; ++r) {
        unsigned long long head = (pos == 0) ? key[0] : (pos == 1) ? key[1] :
                                  (pos == 2) ? key[2] : (pos == 3) ? key[3] : 0ULL;
        unsigned long long mx = wavemax64(head);
        if (head == mx && head != 0ULL) pos++;
        float sc = unpack_val(mx);
        int id = unpack_id(mx);
        tscore[r] = sc;
        tlp[r] = sc * lpen;
        ttok[r] = id % VOCABSZ;
        tbeam[r] = id / VOCABSZ;
        tfin[r] = (ttok[r] == EOS_TOK) ? 1 : 0;
    }

    int aidx[4];
    {
        float curr[8];
#pragma unroll
        for (int j = 0; j < 8; ++j) curr[j] = tscore[j] + (tfin[j] ? -NEGINF : 0.0f);
        unsigned int used = 0;
#pragma unroll
        for (int r = 0; r < 4; ++r) {
            float bv = 0.f; int bj = -1;
#pragma unroll
            for (int j = 0; j < 8; ++j) {
                bool skip = (used >> j) & 1u;
                bool better = !skip && (bj < 0 || curr[j] > bv);
                if (better) { bv = curr[j]; bj = j; }
            }
            used |= 1u << bj; aidx[r] = bj;
        }
    }
    int fidx[4]; float nfsc[4]; int nffl[4];
    {
        float fscand[12]; int fflcand[12];
#pragma unroll
        for (int j = 0; j < 4; ++j) { fscand[j] = fsc[j]; fflcand[j] = ffl[j]; }
#pragma unroll
        for (int q = 0; q < 8; ++q) {
            float t1 = tscore[q] + (tfin[q] ? 0.0f : -NEGINF);
            float t2 = t1 + (bf_old ? -NEGINF : 0.0f);
            fscand[4 + q] = t2; fflcand[4 + q] = tfin[q];
        }
        unsigned int used = 0;
#pragma unroll
        for (int r = 0; r < 4; ++r) {
            float bv = 0.f; int bj = -1;
#pragma unroll
            for (int j = 0; j < 12; ++j) {
                bool skip = (used >> j) & 1u;
                bool better = !skip && (bj < 0 || fscand[j] > bv);
                if (better) { bv = fscand[j]; bj = j; }
            }
            used |= 1u << bj; fidx[r] = bj;
            nfsc[r] = bv;
        }
#pragma unroll
        for (int r = 0; r < 4; ++r) {
            int bj = fidx[r]; int fl = 0;
#pragma unroll
            for (int j = 0; j < 12; ++j) if (bj == j) fl = fflcand[j];
            nffl[r] = fl;
        }
    }

    if (tid == 0) {
#pragma unroll
        for (int r = 0; r < 8; ++r) { s_tlp[r] = tlp[r]; s_ttok[r] = ttok[r]; s_tbeam[r] = tbeam[r]; }
#pragma unroll
        for (int r = 0; r < 4; ++r) { s_aidx[r] = aidx[r]; s_fidx[r] = fidx[r]; s_nfsc[r] = nfsc[r]; s_nffl[r] = nffl[r]; }
    }
    __syncthreads();

    { int k = tid >> 4, p = tid & 15;
      int j = s_aidx[k];
      int val = (p == t + 1) ? s_ttok[j] : aseq_old[s_tbeam[j]][p];
      alive_seq[(b * BEAM + k) * MAXLEN + p] = val;
      int fi = s_fidx[k]; int fval;
      if (fi < 4) fval = fseq_old[fi][p];
      else { int q = fi - 4; fval = (p == t + 1) ? s_ttok[q] : aseq_old[s_tbeam[q]][p]; }
      fin_seq[(b * BEAM + k) * MAXLEN + p] = fval; }

    if (tid < 4) {
        alive_lp[b * BEAM + tid] = s_tlp[s_aidx[tid]];
        fin_scores[b * BEAM + tid] = s_nfsc[tid];
        fin_flags[b * BEAM + tid] = s_nffl[tid];
    }
    if (tid == 0) {
        float lb = s_tlp[s_aidx[0]] / lpen;
        float lowest = nfsc[0] * (nffl[0] ? 1.f : 0.f);
        int allf = nffl[0];
#pragma unroll
        for (int k2 = 1; k2 < 4; ++k2) {
            float pz = nfsc[k2] * (nffl[k2] ? 1.f : 0.f);
            lowest = fminf(lowest, pz);
            allf = allf && nffl[k2];
        }
        lowest = lowest + (allf ? 0.f : -NEGINF);
        batch_fin[b] = bf_old || (lowest >= lb);
    }
}

// ---------------- output: fin_seq[:,0,:] as float ----------------
__global__ __launch_bounds__(256) void k_out(const int* __restrict__ fin_seq, float* __restrict__ out) {
    int tid = threadIdx.x;
    if (tid < BATCH * MAXLEN) {
        int b = tid / MAXLEN, p = tid % MAXLEN;
        out[tid] = (float)fin_seq[(b * BEAM + 0) * MAXLEN + p];
    }
}

extern "C" void kernel_launch(void* const* d_in, const int* in_sizes, int n_in,
                              void* d_out, int out_size, void* d_ws, size_t ws_size,
                              hipStream_t stream) {
    const int*   src  = (const int*)d_in[0];
    const float* Esrc = (const float*)d_in[1];
    const float* Etgt = (const float*)d_in[2];
    const float* W    = (const float*)d_in[3];
    const float* bias = (const float*)d_in[4];
    float* out = (float*)d_out;

    const size_t slab = (size_t)NROWS * VOCABSZ * 4;  // 8.192 MB
    const bool big = ws_size >= 4 * slab + (1u << 20);
    const int NZ = big ? 4 : 1;

    char* p = (char*)d_ws;
    float* partial    = (float*)p; p += NZ * slab;
    float* pooled     = (float*)p; p += BATCH * DIM * 4;
    float* xT         = (float*)p; p += DIM * NROWS * 4;
    float* pp         = (float*)p; p += BATCH * PCH * DIM * 4;   // 256 KB
    float* pcnt       = (float*)p; p += BATCH * PCH * 4;
    float* pm         = (float*)p; p += NROWS * CHUNKS * 4;
    float* ps         = (float*)p; p += NROWS * CHUNKS * 4;
    float* ptopv      = (float*)p; p += NROWS * CHUNKS * 8 * 4;
    int*   ptopi      = (int*)p;   p += NROWS * CHUNKS * 8 * 4;
    int*   alive_seq  = (int*)p;   p += NROWS * MAXLEN * 4;
    int*   fin_seq    = (int*)p;   p += NROWS * MAXLEN * 4;
    float* alive_lp   = (float*)p; p += NROWS * 4;
    float* fin_scores = (float*)p; p += NROWS * 4;
    int*   fin_flags  = (int*)p;   p += NROWS * 4;
    int*   batch_fin  = (int*)p;   p += BATCH * 4;

    k_pool2<<<dim3(BATCH, PCH), DIM, 0, stream>>>(src, Esrc, pp, pcnt);
    k_poolred<<<BATCH, DIM, 0, stream>>>(pp, pcnt, pooled);
    k_init<<<1, 1024, 0, stream>>>(alive_seq, alive_lp, fin_seq, fin_scores, fin_flags, batch_fin);
    for (int t = 0; t < MAXLEN - 1; ++t) {
        k_x<<<NROWS, DIM, 0, stream>>>(Etgt, pooled, alive_seq, t, xT);
        if (big) {
            k_gemm4<DIM/4><<<dim3(VOCABSZ / 64, 1, 4), 256, 0, stream>>>(xT, W, partial);
            k_part<4><<<dim3(NROWS, CHUNKS), 1024, 0, stream>>>(partial, bias, pm, ps, ptopv, ptopi);
        } else {
            k_gemm4<DIM><<<dim3(VOCABSZ / 64, 1, 1), 256, 0, stream>>>(xT, W, partial);
            k_part<1><<<dim3(NROWS, CHUNKS), 1024, 0, stream>>>(partial, bias, pm, ps, ptopv, ptopi);
        }
        k_mergesel<<<BATCH, 64, 0, stream>>>(pm, ps, ptopv, ptopi, alive_seq, alive_lp,
                                             fin_seq, fin_scores, fin_flags, batch_fin, t);
    }
    k_out<<<1, 256, 0, stream>>>(fin_seq, out);
}